// Round 1
// baseline (45.663 us; speedup 1.0000x reference)
//
#include <hip/hip_runtime.h>
#include <hip/hip_bf16.h>

// Bundle-adjustment residual:
//   p = poses[poses_idx]                       (7 floats: t[3], q[4])
//   pts = [patch_coords[patch_idx], elev[patch_idx]]  (3 floats)
//   rotated = quat_rotate(normalize(q), pts) + t
//   proj = cart2polar(rotated)                 (r, az, el)
//   out  = (proj - target) * weight
// One thread per observation; all math in fp32.

__global__ __launch_bounds__(256) void ba_residual_kernel(
    const float* __restrict__ poses,         // [4096,7]
    const float* __restrict__ patch_coords,  // [262144,2]
    const float* __restrict__ elev,          // [262144,1]
    const int*   __restrict__ poses_idx,     // [NOBS]
    const int*   __restrict__ patch_idx,     // [NOBS]
    const float* __restrict__ target,        // [NOBS,3]
    const float* __restrict__ weights,       // [NOBS,1]
    float*       __restrict__ out,           // [NOBS,3]
    int n)
{
    int i = blockIdx.x * blockDim.x + threadIdx.x;
    if (i >= n) return;

    int pi = poses_idx[i];
    int qi = patch_idx[i];

    // Pose gather (cached: 4096*28B = 114 KB)
    const float* p = poses + (size_t)pi * 7;
    float tx = p[0], ty = p[1], tz = p[2];
    float qx = p[3], qy = p[4], qz = p[5], qw = p[6];
    float inv = rsqrtf(qx*qx + qy*qy + qz*qz + qw*qw);
    qx *= inv; qy *= inv; qz *= inv; qw *= inv;

    // Patch point gather (3 MB total, L2-resident)
    float2 pc = *reinterpret_cast<const float2*>(patch_coords + (size_t)qi * 2);
    float px = pc.x, py = pc.y, pz = elev[qi];

    // uv = cross(qv, pts)
    float ux = qy*pz - qz*py;
    float uy = qz*px - qx*pz;
    float uz = qx*py - qy*px;
    // cross(qv, uv)
    float cx = qy*uz - qz*uy;
    float cy = qz*ux - qx*uz;
    float cz = qx*uy - qy*ux;
    // rotated = pts + 2*(qw*uv + cross(qv,uv)) + t
    float rx = px + 2.0f*(qw*ux + cx) + tx;
    float ry = py + 2.0f*(qw*uy + cy) + ty;
    float rz = pz + 2.0f*(qw*uz + cz) + tz;

    // cart2polar (matches reference: r = sqrt(rho^2 + z^2))
    float rho = sqrtf(rx*rx + ry*ry);
    float r   = sqrtf(rho*rho + rz*rz);
    float az  = atan2f(ry, rx);
    float el  = atan2f(rz, rho);

    float w  = weights[i];
    float t0 = target[(size_t)i*3 + 0];
    float t1 = target[(size_t)i*3 + 1];
    float t2 = target[(size_t)i*3 + 2];

    out[(size_t)i*3 + 0] = (r  - t0) * w;
    out[(size_t)i*3 + 1] = (az - t1) * w;
    out[(size_t)i*3 + 2] = (el - t2) * w;
}

extern "C" void kernel_launch(void* const* d_in, const int* in_sizes, int n_in,
                              void* d_out, int out_size, void* d_ws, size_t ws_size,
                              hipStream_t stream) {
    const float* poses        = (const float*)d_in[0];
    const float* patch_coords = (const float*)d_in[1];
    const float* elev         = (const float*)d_in[2];
    const int*   poses_idx    = (const int*)d_in[3];
    const int*   patch_idx    = (const int*)d_in[4];
    const float* target       = (const float*)d_in[5];
    const float* weights      = (const float*)d_in[6];
    float*       out          = (float*)d_out;

    int n = in_sizes[3];  // NUM_OBS
    int block = 256;
    int grid = (n + block - 1) / block;
    ba_residual_kernel<<<grid, block, 0, stream>>>(
        poses, patch_coords, elev, poses_idx, patch_idx, target, weights, out, n);
}